// Round 7
// baseline (539.844 us; speedup 1.0000x reference)
//
#include <hip/hip_runtime.h>

// Problem constants (B, Cin, Cout, H, W) = (8, 256, 256, 128, 128)
#define BATCH 8
#define CIN   256
#define COUT  256
#define HH    128
#define WW    128
#define HW    (HH*WW)          // 16384

typedef __bf16 bf16x8 __attribute__((ext_vector_type(8)));
typedef float  f32x4  __attribute__((ext_vector_type(4)));
typedef unsigned short u16x8 __attribute__((ext_vector_type(8)));

__device__ __forceinline__ unsigned short f2bf(float f) {
    unsigned u = __float_as_uint(f);
    unsigned r = (u + 0x7fffu + ((u >> 16) & 1u)) >> 16;   // round-to-nearest-even
    return (unsigned short)r;
}

// Swizzle for 8x16B-slot rows at 128B row stride. Bijective on r mod 8 AND on
// (4t) mod 32 -> full bank spread for both the conv's stride-4-row writes and
// the MFMA's stride-1-row reads.
__device__ __forceinline__ int swz8(int r) { return (r ^ (r >> 2)) & 7; }

// ---------------------------------------------------------------------------
// FUSED kernel: per block (b, h, mt) computes out[b][mt*128 .. +127][h][0..127].
// R6 post-mortem: 375us, write-only 134MB @ 355GB/s -> stall-bound. Cause:
// fusing dropped the split kernel's LDS staging of dw -> 288 dependent scalar
// global loads per thread feeding the conv FMA chain at 12 waves/CU.
// R7: stage dw (256 ch x 9) into LDS once per block, padded to 12 floats/ch
// (2x ds_read_b128 + 1 b32 per ci, 16B-aligned, broadcast per 32-lane group).
// Everything else identical to R6.
// K-loop over 4 chunks of 64 cin:
//   A-prep: lA[row][k] = bf16(pw + delta)   (swizzled, ds_write_b128)
//   conv:   lB[w][c]   = bf16(dwconv3x3(x)) (swizzled, ds_write_b128)
//   barrier; 2x16 MFMA 16x16x32; barrier.
// Floor: x 134MB read + out 134MB write ~= 45us.
// XCD swizzle: XCD owns batch; mt fastest (x-tile shared), h next (halo L2).
// ---------------------------------------------------------------------------
__global__ __launch_bounds__(256) void fused_kernel(
    const float* __restrict__ x, const float* __restrict__ dw,
    const float* __restrict__ delta, const float* __restrict__ pw,
    float* __restrict__ out)
{
    __shared__ unsigned short lA[128 * 64];   // [m-row][slot^swz8(row)] 16KB
    __shared__ unsigned short lB[128 * 64];   // [w-row][slot^swz8(w)]   16KB
    __shared__ float kw[256 * 12];            // dw staged, padded stride 12 (12KB)

    const int b     = (int)blockIdx.x & 7;    // batch == XCD
    const int inner = (int)blockIdx.x >> 3;   // 0..255 within XCD
    const int mt    = inner & 1;              // Cout half, fastest
    const int h     = inner >> 1;             // 0..127
    const int tid   = threadIdx.x;

    // ---- stage dw: thread c copies its 9 weights (once per block) ----
    {
        const float* s = dw + (size_t)tid * 9;
        float* d = kw + tid * 12;
        #pragma unroll
        for (int j = 0; j < 9; ++j) d[j] = s[j];
    }
    __syncthreads();

    // MFMA decomposition (identical to the proven R1 gemm)
    const int lane = tid & 63;
    const int wv   = tid >> 6;
    const int wm   = (wv & 1) * 64;
    const int wn   = (wv >> 1) * 64;
    const int q    = lane >> 4;     // quad 0..3
    const int rrow = lane & 15;

    // conv decomposition
    const int wq = tid & 31;        // w-quad: w0..w0+3
    const int cs = tid >> 5;        // 0..7: 8 contiguous channels cs*8..cs*8+7
    const int w0 = wq * 4;

    f32x4 acc[4][4] = {};

    const float* deltab = delta + (size_t)b * COUT * CIN;

    for (int kc = 0; kc < 4; ++kc) {
        // ---- A-prep: lA[row][k] = bf16(pw[mt*128+row][kc*64+k] + delta[b][...]) ----
        #pragma unroll
        for (int r = 0; r < 4; ++r) {
            const int i   = r * 256 + tid;    // 16B chunk id 0..1023
            const int row = i >> 3;           // 0..127
            const int ls  = i & 7;            // logical slot
            const size_t goff = (size_t)(mt * 128 + row) * CIN + kc * 64 + ls * 8;
            const float4 p0 = *(const float4*)(pw + goff);
            const float4 p1 = *(const float4*)(pw + goff + 4);
            const float4 d0 = *(const float4*)(deltab + goff);
            const float4 d1 = *(const float4*)(deltab + goff + 4);
            u16x8 v;
            v[0] = f2bf(p0.x + d0.x); v[1] = f2bf(p0.y + d0.y);
            v[2] = f2bf(p0.z + d0.z); v[3] = f2bf(p0.w + d0.w);
            v[4] = f2bf(p1.x + d1.x); v[5] = f2bf(p1.y + d1.y);
            v[6] = f2bf(p1.z + d1.z); v[7] = f2bf(p1.w + d1.w);
            *(u16x8*)&lA[row * 64 + (ls ^ swz8(row)) * 8] = v;
        }

        // ---- conv: this chunk's 64 channels; thread: 4 w x 8 contiguous c ----
        u16x8 v0, v1, v2, v3;   // bf16 outputs for w0..w0+3, elems = ci
        #pragma unroll
        for (int ci = 0; ci < 8; ++ci) {
            const int gc = kc * 64 + cs * 8 + ci;        // global cin
            const float* xp = x + ((size_t)(b * CIN + gc)) * HW;
            // weights from LDS (broadcast per 32-lane group, 16B-aligned)
            const float4 ka = *(const float4*)(kw + gc * 12);      // k[0..3]
            const float4 kb = *(const float4*)(kw + gc * 12 + 4);  // k[4..7]
            const float  k8 = kw[gc * 12 + 8];
            const float kk_[9] = {ka.x, ka.y, ka.z, ka.w, kb.x, kb.y, kb.z, kb.w, k8};
            float a0 = 0.f, a1 = 0.f, a2 = 0.f, a3 = 0.f;
            #pragma unroll
            for (int dy = 0; dy < 3; ++dy) {
                const int r = h + dy - 1;
                float4 v = {0.f, 0.f, 0.f, 0.f};
                if (r >= 0 && r < HH) v = *(const float4*)(xp + r * WW + w0);
                float lft = __shfl_up(v.w, 1);    // lane-1's last element
                float rgt = __shfl_down(v.x, 1);  // lane+1's first element
                if (wq == 0)  lft = 0.f;          // w=-1 pad
                if (wq == 31) rgt = 0.f;          // w=128 pad
                const float k0 = kk_[dy * 3 + 0], k1 = kk_[dy * 3 + 1], k2 = kk_[dy * 3 + 2];
                a0 += k0 * lft + k1 * v.x + k2 * v.y;
                a1 += k0 * v.x + k1 * v.y + k2 * v.z;
                a2 += k0 * v.y + k1 * v.z + k2 * v.w;
                a3 += k0 * v.z + k1 * v.w + k2 * rgt;
            }
            v0[ci] = f2bf(a0); v1[ci] = f2bf(a1);
            v2[ci] = f2bf(a2); v3[ci] = f2bf(a3);
        }
        // c-group cs is logical slot cs; 4 rows w0..w0+3
        *(u16x8*)&lB[(w0 + 0) * 64 + (cs ^ swz8(w0 + 0)) * 8] = v0;
        *(u16x8*)&lB[(w0 + 1) * 64 + (cs ^ swz8(w0 + 1)) * 8] = v1;
        *(u16x8*)&lB[(w0 + 2) * 64 + (cs ^ swz8(w0 + 2)) * 8] = v2;
        *(u16x8*)&lB[(w0 + 3) * 64 + (cs ^ swz8(w0 + 3)) * 8] = v3;

        __syncthreads();

        // ---- MFMA: K=64 in 2 kk-steps ----
        #pragma unroll
        for (int kk = 0; kk < 2; ++kk) {
            bf16x8 af[4], bfv[4];
            #pragma unroll
            for (int i = 0; i < 4; ++i) {
                const int ra = wm + i * 16 + rrow;
                const int rb = wn + i * 16 + rrow;
                af[i]  = *(const bf16x8*)&lA[ra * 64 + ((kk * 4 + q) ^ swz8(ra)) * 8];
                bfv[i] = *(const bf16x8*)&lB[rb * 64 + ((kk * 4 + q) ^ swz8(rb)) * 8];
            }
            #pragma unroll
            for (int i = 0; i < 4; ++i)
                #pragma unroll
                for (int j = 0; j < 4; ++j)
                    acc[i][j] = __builtin_amdgcn_mfma_f32_16x16x32_bf16(af[i], bfv[j], acc[i][j], 0, 0, 0);
        }
        __syncthreads();   // lA/lB reused next chunk
    }

    // epilogue: C/D map col=lane&15, row=quad*4+reg (proven in R1 gemm)
    float* outp = out + ((size_t)(b * COUT + mt * 128 + wm)) * HW + (size_t)h * WW + wn;
    #pragma unroll
    for (int i = 0; i < 4; ++i)
        #pragma unroll
        for (int j = 0; j < 4; ++j)
            #pragma unroll
            for (int rr = 0; rr < 4; ++rr)
                outp[(size_t)(i * 16 + q * 4 + rr) * HW + j * 16 + rrow] = acc[i][j][rr];
}

// ---------------------------------------------------------------------------
extern "C" void kernel_launch(void* const* d_in, const int* in_sizes, int n_in,
                              void* d_out, int out_size, void* d_ws, size_t ws_size,
                              hipStream_t stream)
{
    const float* x     = (const float*)d_in[0];   // (8,256,128,128)
    const float* delta = (const float*)d_in[1];   // (8,256,256,1,1)
    const float* dw    = (const float*)d_in[2];   // (256,1,3,3)
    const float* pw    = (const float*)d_in[3];   // (256,256,1,1)
    float* out = (float*)d_out;                   // (8,256,128,128)

    // fully fused: no workspace needed
    fused_kernel<<<dim3(2048), dim3(256), 0, stream>>>(x, dw, delta, pw, out);
}

// Round 8
// 318.178 us; speedup vs baseline: 1.6967x; 1.6967x over previous
//
#include <hip/hip_runtime.h>

// Problem constants (B, Cin, Cout, H, W) = (8, 256, 256, 128, 128)
#define BATCH 8
#define CIN   256
#define COUT  256
#define HH    128
#define WW    128
#define HW    (HH*WW)          // 16384

typedef __bf16 bf16x8 __attribute__((ext_vector_type(8)));
typedef float  f32x4  __attribute__((ext_vector_type(4)));
typedef unsigned short u16x8 __attribute__((ext_vector_type(8)));

__device__ __forceinline__ unsigned short f2bf(float f) {
    unsigned u = __float_as_uint(f);
    unsigned r = (u + 0x7fffu + ((u >> 16) & 1u)) >> 16;   // round-to-nearest-even
    return (unsigned short)r;
}

// ---------------------------------------------------------------------------
// Kernel 1: depthwise 3x3 conv (pad=1) -> bf16 Tt[b][p][c], BARRIER-FREE.
// R7 post-mortem: fused kernel structurally latency-bound (3 blk/CU, barrier
// convoy); split conv's stall was its LDS transpose (4 barriers + 3.1M bank
// conflicts + 4B scattered stores). Fix: thread owns 8 CONSECUTIVE channels
// (c = cs*8+ci) so the conv result is a c-contiguous u16x8 -> direct 16B
// global_store_dwordx4 to Tt. No LDS tile, no inner barriers; LDS only for
// the 2.3KB weights. VGPR ~64 -> 8 waves/SIMD; 2048 blocks = 8 blk/CU.
// Prep (W_b = pw + delta) folded in as 64 trailing blocks.
// XCD swizzle: XCD owns batch; hb fastest (halo rows L2-hot).
// ---------------------------------------------------------------------------
#define CONV_BLOCKS 2048   // 64 hb * 4 cb * 8 b
#define PREP_BLOCKS 64

__global__ __launch_bounds__(256) void dwconv_prep_kernel(
    const float* __restrict__ x, const float* __restrict__ dw,
    const float* __restrict__ delta, const float* __restrict__ pw,
    unsigned short* __restrict__ Tt, unsigned short* __restrict__ Wb)
{
    const int tid = threadIdx.x;

    if ((int)blockIdx.x >= CONV_BLOCKS) {
        // ---- prep path: W_b[b][o][c] = bf16(pw[o][c] + delta[b][o][c]) ----
        // 64 blocks * 256 threads * 8 quads = 131072 quads = 8*256*256/4.
        const int t0 = (((int)blockIdx.x - CONV_BLOCKS) * 256 + tid) * 8;
        #pragma unroll
        for (int qq = 0; qq < 8; ++qq) {
            const int i = t0 + qq;                       // quad index
            float4 d = *(const float4*)(delta + (size_t)i * 4);
            const int j = (i * 4) & (COUT * CIN - 1);    // pw index (o*256+c)
            float4 p = *(const float4*)(pw + j);
            ushort4 r;
            r.x = f2bf(d.x + p.x);
            r.y = f2bf(d.y + p.y);
            r.z = f2bf(d.z + p.z);
            r.w = f2bf(d.w + p.w);
            *(ushort4*)(Wb + (size_t)i * 4) = r;
        }
        return;
    }

    __shared__ float kw[64 * 9];   // this block's 64 channels' weights (2.3KB)

    // bijective XCD swizzle: XCD (bid&7) owns batch (bid&7); hb fastest.
    const int L  = ((int)blockIdx.x & 7) * (CONV_BLOCKS / 8) + ((int)blockIdx.x >> 3);
    const int hb = L & 63;          // 2 h-rows: hb*2, hb*2+1
    const int cb = (L >> 6) & 3;    // 64-channel group
    const int b  = L >> 8;          // batch == XCD index

    // stage weights: 576 floats = 144 float4 (proven R3 pattern)
    if (tid < 144) {
        float4 v = *(const float4*)(dw + (size_t)cb * 576 + (size_t)tid * 4);
        *(float4*)(kw + tid * 4) = v;
    }
    __syncthreads();   // the ONLY barrier

    const int wq = tid & 31;     // w-quad: covers w0..w0+3
    const int cs = tid >> 5;     // 0..7: channels cs*8 .. cs*8+7 (consecutive!)
    const int w0 = wq * 4;

    #pragma unroll
    for (int hh = 0; hh < 2; ++hh) {
        const int h = hb * 2 + hh;
        u16x8 v0, v1, v2, v3;    // bf16 outputs for w0..w0+3; elem index = ci
        #pragma unroll
        for (int ci = 0; ci < 8; ++ci) {
            const int c  = cs * 8 + ci;                  // local channel 0..63
            const float* xp = x + ((size_t)(b * CIN + cb * 64 + c)) * HW;
            const float* kc = kw + c * 9;
            float a0 = 0.f, a1 = 0.f, a2 = 0.f, a3 = 0.f;
            #pragma unroll
            for (int dy = 0; dy < 3; ++dy) {
                const int r = h + dy - 1;
                float4 v = {0.f, 0.f, 0.f, 0.f};
                if (r >= 0 && r < HH) v = *(const float4*)(xp + r * WW + w0);
                float lft = __shfl_up(v.w, 1);    // lane-1's last element
                float rgt = __shfl_down(v.x, 1);  // lane+1's first element
                if (wq == 0)  lft = 0.f;          // w=-1 pad
                if (wq == 31) rgt = 0.f;          // w=128 pad
                const float k0 = kc[dy * 3 + 0], k1 = kc[dy * 3 + 1], k2 = kc[dy * 3 + 2];
                a0 += k0 * lft + k1 * v.x + k2 * v.y;
                a1 += k0 * v.x + k1 * v.y + k2 * v.z;
                a2 += k0 * v.y + k1 * v.z + k2 * v.w;
                a3 += k0 * v.z + k1 * v.w + k2 * rgt;
            }
            v0[ci] = f2bf(a0); v1[ci] = f2bf(a1);
            v2[ci] = f2bf(a2); v3[ci] = f2bf(a3);
        }
        // direct 16B stores: Tt[b][p = h*128 + w][cb*64 + cs*8 .. +7]
        unsigned short* tp = Tt + ((size_t)b * HW + (size_t)h * WW + w0) * CIN
                                + cb * 64 + cs * 8;
        *(u16x8*)(tp)            = v0;
        *(u16x8*)(tp + CIN)      = v1;
        *(u16x8*)(tp + 2 * CIN)  = v2;
        *(u16x8*)(tp + 3 * CIN)  = v3;
    }
}

// ---------------------------------------------------------------------------
// Kernel 2: per-batch GEMM  out[b][o][p] = sum_c Wb[b][o][c] * Tt[b][p][c]
// UNCHANGED from R1/R3 (passed on HW twice): BK=64, XOR-swizzled LDS via
// pre-swizzled global source, XCD swizzle batch==XCD.
// ---------------------------------------------------------------------------
__global__ __launch_bounds__(256) void gemm_kernel(
    const unsigned short* __restrict__ Wb,
    const unsigned short* __restrict__ Tt,
    float* __restrict__ out)
{
    __shared__ unsigned short lA[128 * 64];   // [row][slot ^ (row&7)], 16B slots
    __shared__ unsigned short lB[128 * 64];

    // 2048 blocks: XCD (bid&7) owns logical range 256 = one batch; within it
    // mt toggles fastest, then nt.
    const int L  = ((int)blockIdx.x & 7) * 256 + ((int)blockIdx.x >> 3);
    const int mt = L & 1;
    const int nt = (L >> 1) & 127;
    const int b  = L >> 8;
    const int tid = threadIdx.x;

    const unsigned short* Ab = Wb + ((size_t)b * COUT + mt * 128) * CIN;   // [128][256]
    const unsigned short* Bb = Tt + ((size_t)b * HW + nt * 128) * CIN;     // [128][256]

    const int lane = tid & 63;
    const int wv   = tid >> 6;
    const int wm   = (wv & 1) * 64;
    const int wn   = (wv >> 1) * 64;
    const int q    = lane >> 4;     // quad 0..3
    const int rrow = lane & 15;

    f32x4 acc[4][4] = {};

    for (int k0 = 0; k0 < CIN; k0 += 64) {
        #pragma unroll
        for (int r = 0; r < 4; ++r) {
            const int i     = r * 256 + tid;    // 16B chunk id, 0..1023
            const int row   = i >> 3;           // 0..127
            const int pslot = i & 7;            // physical 16B slot in row
            const int lslot = pslot ^ (row & 7);// logical slot fetched here
            const unsigned short* ga = Ab + (size_t)row * CIN + k0 + lslot * 8;
            const unsigned short* gb = Bb + (size_t)row * CIN + k0 + lslot * 8;
            __builtin_amdgcn_global_load_lds(
                (const __attribute__((address_space(1))) void*)ga,
                (__attribute__((address_space(3))) void*)(lA + (size_t)i * 8),
                16, 0, 0);
            __builtin_amdgcn_global_load_lds(
                (const __attribute__((address_space(1))) void*)gb,
                (__attribute__((address_space(3))) void*)(lB + (size_t)i * 8),
                16, 0, 0);
        }
        __syncthreads();

        #pragma unroll
        for (int kk = 0; kk < 2; ++kk) {
            bf16x8 af[4], bfv[4];
            const int slot = (kk * 4 + q) ^ (rrow & 7);   // row&7 == rrow&7 here
            #pragma unroll
            for (int i = 0; i < 4; ++i) {
                af[i]  = *(const bf16x8*)&lA[(wm + i * 16 + rrow) * 64 + slot * 8];
                bfv[i] = *(const bf16x8*)&lB[(wn + i * 16 + rrow) * 64 + slot * 8];
            }
            #pragma unroll
            for (int i = 0; i < 4; ++i)
                #pragma unroll
                for (int j = 0; j < 4; ++j)
                    acc[i][j] = __builtin_amdgcn_mfma_f32_16x16x32_bf16(af[i], bfv[j], acc[i][j], 0, 0, 0);
        }
        __syncthreads();
    }

    // epilogue: C/D map col=lane&15, row=quad*4+reg
    float* outp = out + ((size_t)b * COUT + mt * 128 + wm) * HW + (size_t)nt * 128 + wn;
    #pragma unroll
    for (int i = 0; i < 4; ++i)
        #pragma unroll
        for (int j = 0; j < 4; ++j)
            #pragma unroll
            for (int rr = 0; rr < 4; ++rr)
                outp[(size_t)(i * 16 + q * 4 + rr) * HW + j * 16 + rrow] = acc[i][j][rr];
}

// ---------------------------------------------------------------------------
extern "C" void kernel_launch(void* const* d_in, const int* in_sizes, int n_in,
                              void* d_out, int out_size, void* d_ws, size_t ws_size,
                              hipStream_t stream)
{
    const float* x     = (const float*)d_in[0];   // (8,256,128,128)
    const float* delta = (const float*)d_in[1];   // (8,256,256,1,1)
    const float* dw    = (const float*)d_in[2];   // (256,1,3,3)
    const float* pw    = (const float*)d_in[3];   // (256,256,1,1)
    float* out = (float*)d_out;                   // (8,256,128,128)

    // workspace: Tt bf16 [8][16384][256] = 64 MiB, then Wb bf16 [8][256][256] = 1 MiB
    unsigned short* Tt = (unsigned short*)d_ws;
    unsigned short* Wb = (unsigned short*)((char*)d_ws + (size_t)BATCH * HW * CIN * 2);

    dwconv_prep_kernel<<<dim3(CONV_BLOCKS + PREP_BLOCKS), dim3(256), 0, stream>>>(
        x, dw, delta, pw, Tt, Wb);
    gemm_kernel<<<dim3(2048), dim3(256), 0, stream>>>(Wb, Tt, out);
}